// Round 9
// baseline (555.171 us; speedup 1.0000x reference)
//
#include <hip/hip_runtime.h>

// DIAGNOSTIC ROUND: Round-7 kernel (best, 465.1 us) launched TWICE.
// The second launch writes byte-identical data (idempotent), so correctness
// is unchanged and dur_us_new - 465 measures the kernel's standalone
// duration K directly — disambiguating "kernel ~155us (write-path penalty)"
// from "kernel ~80us (roofline) + ~75us fixed harness reset overhead".
//
// Problem constants:
//   k,v: [B=2, C=128, Hc=48, Wc=48] fp32; NUM_HEADS=8 -> hd=16
//   WINDOW=5 -> K=25 offsets, r=2; query grid 96x96, scale=2
// Outputs: k_nb [2,8,25,16,96,96] | v_nb same | mask [2,8,25,96,96]

#define KV_ELEMS  58982400LL
#define MASK_OFF  117964800LL

typedef float f32x4 __attribute__((ext_vector_type(4)));

__global__ __launch_bounds__(256) void fused_expand_kernel(
    const float* __restrict__ k, const float* __restrict__ v,
    float* __restrict__ out_k, float* __restrict__ out_v,
    float* __restrict__ out_m) {
    const int t  = blockIdx.x * 256 + threadIdx.x;
    const int kk = blockIdx.y;           // 0..24
    const int z  = blockIdx.z;           // b*8+h, 0..15

    const int q  = t / 24;               // = d*96 + y
    const int x4 = t - q * 24;
    const int d  = q / 96;
    const int y  = q - d * 96;

    // wave-uniform -> scalar unit
    const int kq = kk / 5;
    const int dy = kq - 2;
    const int dx = kk - kq * 5 - 2;

    const int yy  = (y >> 1) + dy;
    const bool vy = (unsigned)yy < 48u;
    const int xc0 = 2 * x4 + dx;
    const int xc1 = xc0 + 1;
    const bool v0 = vy && ((unsigned)xc0 < 48u);
    const bool v1 = vy && ((unsigned)xc1 < 48u);

    const int yc = vy ? yy : 0;
    const int x0 = min(max(xc0, 0), 47);
    const int x1 = min(max(xc1, 0), 47);

    const int base = ((z * 16 + d) * 48 + yc) * 48;
    float k0 = k[base + x0];
    float k1 = k[base + x1];
    float w0 = v[base + x0];
    float w1 = v[base + x1];
    k0 = v0 ? k0 : 0.0f;
    k1 = v1 ? k1 : 0.0f;
    w0 = v0 ? w0 : 0.0f;
    w1 = v1 ? w1 : 0.0f;

    const int slice = z * 25 + kk;
    const int o = slice * 36864 + t;
    reinterpret_cast<f32x4*>(out_k)[o] = (f32x4){k0, k0, k1, k1};
    reinterpret_cast<f32x4*>(out_v)[o] = (f32x4){w0, w0, w1, w1};

    if (blockIdx.x < 9) {  // block-uniform: exactly the d==0 blocks
        const float m0 = v0 ? 1.0f : 0.0f;
        const float m1 = v1 ? 1.0f : 0.0f;
        reinterpret_cast<f32x4*>(out_m)[slice * 2304 + t] =
            (f32x4){m0, m0, m1, m1};
    }
}

extern "C" void kernel_launch(void* const* d_in, const int* in_sizes, int n_in,
                              void* d_out, int out_size, void* d_ws, size_t ws_size,
                              hipStream_t stream) {
    const float* k = (const float*)d_in[0];
    const float* v = (const float*)d_in[1];
    float* out = (float*)d_out;
    float* out_k = out;
    float* out_v = out + KV_ELEMS;
    float* out_m = out + MASK_OFF;

    // Launch 1: produces the output.
    fused_expand_kernel<<<dim3(144, 25, 16), 256, 0, stream>>>(
        k, v, out_k, out_v, out_m);
    // Launch 2: identical (idempotent) — exists purely to measure K.
    fused_expand_kernel<<<dim3(144, 25, 16), 256, 0, stream>>>(
        k, v, out_k, out_v, out_m);
}